// Round 19
// baseline (54.098 us; speedup 1.0000x reference)
//
#include <hip/hip_runtime.h>
#include <hip/hip_bf16.h>
#include <math.h>

#define S_LEN 128
#define D_DIM 768
#define P_PAIRS 1024
#define B_BATCH 16

typedef __attribute__((ext_vector_type(8))) short bf16x8;
typedef __attribute__((ext_vector_type(4))) float f32x4;

#define PB_UNITS (B_BATCH * (D_DIM / 64))            // 192
#define T1_UNITS ((2304 / 128) * (1536 / 64))        // 18*24 = 432
#define T2_UNITS ((1536 / 128) * (768 / 64))         // 12*12 = 144
#define T3_UNITS ((768 / 128) * (128 / 64))          // 6*2   = 12
#define G1_TILES (24 * 16)                           // 384 GEMM1 tiles

union SmemU {
    struct {
        ushort semb[128][64];    // emb chunk, bf16-rounded
        ushort spref[128][64];   // prefix max (bf16)
        ushort ssuf[128][64];    // suffix max (bf16)
        ushort smean[64];
        float  lred[3][4][64];
        int    li;
    } pb;                        // ~52.4 KB -> 3 blocks/CU
    float t128[128][65];         // transpose tile (33.3 KB)
};

union GSmem {
    ushort lds[4][128 * 64];     // GEMM 4-buffer (64 KB)
    float  t128[128][65];        // transpose tile (33.3 KB)
};

__device__ __forceinline__ ushort f2bf(float f) {
    __hip_bfloat16 h = __float2bfloat16(f);
    return *(ushort*)&h;
}

__device__ __forceinline__ float bf2f(ushort u) {
    unsigned int x = ((unsigned int)u) << 16;
    float f;
    __builtin_memcpy(&f, &x, 4);
    return f;
}

__device__ __forceinline__ void gload16(const void* g, void* l) {
    __builtin_amdgcn_global_load_lds(
        (const __attribute__((address_space(1))) void*)g,
        (__attribute__((address_space(3))) void*)l, 16, 0, 0);
}

// ---------------------------------------------------------------------------
// 128(K)x64(N) transpose unit: in[K,N] f32 -> out[Npad,K] bf16 (zero-pad n>=N)
// (round-13 verified body)
// ---------------------------------------------------------------------------
__device__ __forceinline__ void transpose128_unit(
    float (*t128)[65], const float* __restrict__ in, ushort* __restrict__ out,
    int K, int N, int Npad, int bx, int by, int tid)
{
    int k0 = bx * 128, n0 = by * 64;

    #pragma unroll
    for (int h = 0; h < 2; ++h) {
        int kr = h * 64 + (tid >> 2);
        int nq = (tid & 3) * 16;
        if (n0 + 64 <= N) {
            #pragma unroll
            for (int j = 0; j < 4; ++j) {
                float4 vv = *(const float4*)&in[(size_t)(k0 + kr) * N + n0 + nq + j * 4];
                *(float4*)&t128[kr][nq + j * 4] = vv;
            }
        } else {
            #pragma unroll
            for (int j = 0; j < 16; ++j) {
                int n = n0 + nq + j;
                t128[kr][nq + j] = (n < N) ? in[(size_t)(k0 + kr) * N + n] : 0.f;
            }
        }
    }
    __syncthreads();

    int nr = tid >> 2;            // 0..63 output row (n)
    int kq = (tid & 3) * 32;      // 0,32,64,96
    if (n0 + nr < Npad) {
        ushort tmp[32];
        #pragma unroll
        for (int j = 0; j < 32; ++j) tmp[j] = f2bf(t128[kq + j][nr]);
        ushort* dst = out + (size_t)(n0 + nr) * K + k0 + kq;
        *(bf16x8*)(dst)      = *(bf16x8*)&tmp[0];
        *(bf16x8*)(dst + 8)  = *(bf16x8*)&tmp[8];
        *(bf16x8*)(dst + 16) = *(bf16x8*)&tmp[16];
        *(bf16x8*)(dst + 24) = *(bf16x8*)&tmp[24];
    }
}

// ---------------------------------------------------------------------------
// Fused prep kernel.
//   blocks [0,192):    per-(batch, 64-col-chunk) span scan + X build
//   blocks [192,624):  W1 transpose (128x64 tiles) — 624 <= 768 co-resident
//                      at 3 blocks/CU -> single scheduling round.
// ---------------------------------------------------------------------------
__global__ __launch_bounds__(256) void fused_prep_kernel(
    const float* __restrict__ emb_all,   // [B,S,D]
    const int* __restrict__ span_masks,  // [B,S]
    const int* __restrict__ batch_idx,   // [P]
    const int* __restrict__ aspect_idx,  // [P]
    const int* __restrict__ opinion_idx, // [P]
    ushort* __restrict__ X,              // [P, 3*D] bf16
    const float* __restrict__ W1, ushort* __restrict__ W1t)
{
    __shared__ SmemU sm;
    __shared__ int wsum[4];
    int bid = blockIdx.x;
    int tid = threadIdx.x;

    if (bid < PB_UNITS) {
        // ================= span scan + X build =================
        int b = bid / (D_DIM / 64);
        int chunk = bid % (D_DIM / 64);
        int lane = tid & 63;
        int g = tid >> 6;           // wave/row-group 0..3
        int r0 = g * 32;
        int col = chunk * 64 + lane;

        // parallel li: one mask element per thread, shfl+LDS tree reduce
        {
            int mv = (tid < S_LEN) ? span_masks[b * S_LEN + tid] : 0;
            #pragma unroll
            for (int off = 32; off > 0; off >>= 1)
                mv += __shfl_down(mv, off);
            if (lane == 0) wsum[g] = mv;
            __syncthreads();
            if (tid == 0) sm.pb.li = wsum[0] + wsum[1] + wsum[2] + wsum[3] - 1;
            __syncthreads();
        }
        int li = sm.pb.li;

        const float* embb = emb_all + (size_t)b * S_LEN * D_DIM;

        float v[32];
        #pragma unroll
        for (int r = 0; r < 32; ++r) {
            v[r] = embb[(size_t)(r0 + r) * D_DIM + col];
            sm.pb.semb[r0 + r][lane] = f2bf(v[r]);
        }

        float wmax = -INFINITY, umax = -INFINITY, s = 0.f;
        #pragma unroll
        for (int r = 0; r < 32; ++r) {
            int gr = r0 + r;
            wmax = fmaxf(wmax, (gr == 0) ? -INFINITY : v[r]);
            bool in = (gr >= 1) && (gr < li);
            umax = fmaxf(umax, in ? v[r] : -INFINITY);
            s += in ? v[r] : 0.f;
        }
        sm.pb.lred[0][g][lane] = wmax;
        sm.pb.lred[1][g][lane] = umax;
        sm.pb.lred[2][g][lane] = s;
        __syncthreads();

        float basep = -INFINITY;
        #pragma unroll
        for (int gg = 0; gg < 3; ++gg)
            if (gg < g) basep = fmaxf(basep, sm.pb.lred[0][gg][lane]);
        float bases = -INFINITY;
        #pragma unroll
        for (int gg = 1; gg < 4; ++gg)
            if (gg > g) bases = fmaxf(bases, sm.pb.lred[1][gg][lane]);

        if (g == 0) {
            float tot = sm.pb.lred[2][0][lane] + sm.pb.lred[2][1][lane]
                      + sm.pb.lred[2][2][lane] + sm.pb.lred[2][3][lane];
            int cnt = (li - 1) > 0 ? (li - 1) : 1;
            sm.pb.smean[lane] = f2bf(tot / (float)cnt);
        }

        float m = basep;
        #pragma unroll
        for (int r = 0; r < 32; ++r) {
            int gr = r0 + r;
            m = fmaxf(m, (gr == 0) ? -INFINITY : v[r]);
            sm.pb.spref[gr][lane] = f2bf(m);
        }
        float m2 = bases;
        #pragma unroll
        for (int r = 31; r >= 0; --r) {
            int gr = r0 + r;
            bool in = (gr >= 1) && (gr < li);
            m2 = fmaxf(m2, in ? v[r] : -INFINITY);
            if (gr >= 1) sm.pb.ssuf[gr][lane] = f2bf(m2);
        }
        __syncthreads();

        // pair loop: wave g scans pairs [g*256, (g+1)*256), ballot over batch
        int pbase = g * 256;
        for (int c = 0; c < 256; c += 64) {
            int p = pbase + c + lane;
            int vb = batch_idx[p];
            int va = aspect_idx[p];
            int vo = opinion_idx[p];
            unsigned long long mask = __ballot(vb == b);
            while (mask) {
                int i = __ffsll((long long)mask) - 1;
                mask &= mask - 1;
                int pp = pbase + c + i;
                int a = __shfl(va, i);
                int o = __shfl(vo, i);
                bool both0 = (a == 0) && (o == 0);
                int bnd = (a != 0) ? a : o;
                int oe = (o == 0) ? li : o;
                float ar  = bf2f(sm.pb.semb[a][lane]);
                float orp = bf2f(sm.pb.semb[oe][lane]);
                ushort left, right;
                if (both0) {
                    left  = sm.pb.smean[lane];
                    right = sm.pb.spref[li - 1][lane];
                } else {
                    left  = (bnd == 1)  ? sm.pb.semb[0][lane]
                                        : sm.pb.spref[bnd - 1][lane];
                    right = (bnd == li) ? sm.pb.semb[li][lane]
                                        : sm.pb.ssuf[bnd][lane];
                }
                size_t base = (size_t)pp * (3 * D_DIM) + col;
                X[base]             = f2bf(ar + orp);
                X[base + D_DIM]     = left;
                X[base + 2 * D_DIM] = right;
            }
        }
    } else {
        // ================= W1 transpose (128x64 tiles) =================
        int tb = bid - PB_UNITS;
        transpose128_unit(sm.t128, W1, W1t, 2304, 1536, 1536,
                          tb % (2304 / 128), tb / (2304 / 128), tid);
    }
}

// ---------------------------------------------------------------------------
// GEMM1 launch: blocks [0,384) = MFMA 64x64 tiles (round-14 proven body);
// blocks [384,540) = W2/W3 transposes (outputs needed only by GEMM2/3 —
// stream order guarantees completion before they launch).
// ---------------------------------------------------------------------------
__global__ __launch_bounds__(256, 2) void gemm1_plus_t23(
    const ushort* __restrict__ A,    // X [1024,2304] bf16
    const ushort* __restrict__ Bt,   // W1t [1536,2304] bf16
    const float* __restrict__ bias,  // b1 [1536]
    ushort* __restrict__ Cout,       // H1 [1024,1536] bf16
    const float* __restrict__ W2, ushort* __restrict__ W2t,
    const float* __restrict__ W3, ushort* __restrict__ W3t)
{
    constexpr int M = 1024, N = 1536, K = 2304;
    __shared__ GSmem gs;
    int bid = blockIdx.x;
    int tid = threadIdx.x;

    if (bid >= G1_TILES) {
        int tb = bid - G1_TILES;
        if (tb < T2_UNITS)
            transpose128_unit(gs.t128, W2, W2t, 1536, 768, 768,
                              tb % (1536 / 128), tb / (1536 / 128), tid);
        else {
            tb -= T2_UNITS;
            transpose128_unit(gs.t128, W3, W3t, 768, 121, 128,
                              tb % (768 / 128), tb / (768 / 128), tid);
        }
        return;
    }

    int lane = tid & 63;
    int w = tid >> 6;
    int wr = w >> 1, wc = w & 1;
    int bx = bid % 24, by = bid / 24;
    int rowBase = by * 64;
    int colBase = bx * 64;

    int srow  = lane >> 3;
    int scolb = (((lane & 7) ^ srow) << 4);
    const char* Abase = (const char*)(A  + (size_t)rowBase * K);
    const char* Bbase = (const char*)(Bt + (size_t)colBase * K);
    size_t rstride = (size_t)K * 2;

    f32x4 acc[2][2] = {};
    int nt = K >> 6;

    auto stage = [&](int buf, int t) {
        size_t kb0 = (size_t)t << 7;
        #pragma unroll
        for (int i = 0; i < 2; ++i) {
            int r = w * 16 + i * 8 + srow;
            gload16(Abase + (size_t)r * rstride + kb0 + scolb,
                    &gs.lds[buf][(w * 16 + i * 8) * 64]);
        }
        #pragma unroll
        for (int i = 0; i < 2; ++i) {
            int r = w * 16 + i * 8 + srow;
            gload16(Bbase + (size_t)r * rstride + kb0 + scolb,
                    &gs.lds[buf][(64 + w * 16 + i * 8) * 64]);
        }
    };

    stage(0, 0);
    stage(1, 1);
    stage(2, 2);

    for (int t = 0; t < nt; ++t) {
        int cur = t & 3;
        int ahead = nt - 1 - t;
        if (ahead >= 2)      asm volatile("s_waitcnt vmcnt(8)" ::: "memory");
        else if (ahead == 1) asm volatile("s_waitcnt vmcnt(4)" ::: "memory");
        else                 asm volatile("s_waitcnt vmcnt(0)" ::: "memory");
        __builtin_amdgcn_s_barrier();
        __builtin_amdgcn_sched_barrier(0);

        if (t + 3 < nt) stage((t + 3) & 3, t + 3);

        const char* lb = (const char*)&gs.lds[cur][0];
        int kq = (lane >> 4) << 4;
        bf16x8 af[2][2], bfr[2][2];
        #pragma unroll
        for (int m = 0; m < 2; ++m) {
            int row = wr * 32 + m * 16 + (lane & 15);
            #pragma unroll
            for (int kk = 0; kk < 2; ++kk) {
                int addr = row * 128 + ((kq + kk * 64) ^ ((row & 7) << 4));
                af[m][kk] = *(const bf16x8*)(lb + addr);
            }
        }
        #pragma unroll
        for (int n = 0; n < 2; ++n) {
            int row = 64 + wc * 32 + n * 16 + (lane & 15);
            #pragma unroll
            for (int kk = 0; kk < 2; ++kk) {
                int addr = row * 128 + ((kq + kk * 64) ^ ((row & 7) << 4));
                bfr[n][kk] = *(const bf16x8*)(lb + addr);
            }
        }
        __builtin_amdgcn_s_setprio(1);
        #pragma unroll
        for (int m = 0; m < 2; ++m)
            #pragma unroll
            for (int n = 0; n < 2; ++n)
                #pragma unroll
                for (int kk = 0; kk < 2; ++kk)
                    acc[m][n] = __builtin_amdgcn_mfma_f32_16x16x32_bf16(
                        af[m][kk], bfr[n][kk], acc[m][n], 0, 0, 0);
        __builtin_amdgcn_s_setprio(0);
    }

    #pragma unroll
    for (int m = 0; m < 2; ++m) {
        #pragma unroll
        for (int n = 0; n < 2; ++n) {
            #pragma unroll
            for (int j = 0; j < 4; ++j) {
                int row = rowBase + wr * 32 + m * 16 + (lane >> 4) * 4 + j;
                int col = colBase + wc * 32 + n * 16 + (lane & 15);
                float v = fmaxf(acc[m][n][j] + bias[col], 0.f);
                Cout[(size_t)row * N + col] = f2bf(v);
            }
        }
    }
}

// ---------------------------------------------------------------------------
// GEMM2/3 (round-14 proven body): 64x64 tile, 4 waves, depth-3 pipeline.
// ---------------------------------------------------------------------------
template<int WRITE_BF16, int RELU>
__global__ __launch_bounds__(256, 2) void gemm_mfma(
    const ushort* __restrict__ A,    // [M,K] bf16
    const ushort* __restrict__ Bt,   // [Npad,K] bf16
    const float* __restrict__ bias,  // [N]
    void* __restrict__ Cout,         // [M,N]
    int M, int N, int K)
{
    __shared__ ushort lds[4][128 * 64];
    int tid = threadIdx.x;
    int lane = tid & 63;
    int w = tid >> 6;
    int wr = w >> 1, wc = w & 1;
    int rowBase = blockIdx.y * 64;
    int colBase = blockIdx.x * 64;

    int srow  = lane >> 3;
    int scolb = (((lane & 7) ^ srow) << 4);
    const char* Abase = (const char*)(A  + (size_t)rowBase * K);
    const char* Bbase = (const char*)(Bt + (size_t)colBase * K);
    size_t rstride = (size_t)K * 2;

    f32x4 acc[2][2] = {};
    int nt = K >> 6;

    auto stage = [&](int buf, int t) {
        size_t kb0 = (size_t)t << 7;
        #pragma unroll
        for (int i = 0; i < 2; ++i) {
            int r = w * 16 + i * 8 + srow;
            gload16(Abase + (size_t)r * rstride + kb0 + scolb,
                    &lds[buf][(w * 16 + i * 8) * 64]);
        }
        #pragma unroll
        for (int i = 0; i < 2; ++i) {
            int r = w * 16 + i * 8 + srow;
            gload16(Bbase + (size_t)r * rstride + kb0 + scolb,
                    &lds[buf][(64 + w * 16 + i * 8) * 64]);
        }
    };

    stage(0, 0);
    stage(1, 1);
    stage(2, 2);

    for (int t = 0; t < nt; ++t) {
        int cur = t & 3;
        int ahead = nt - 1 - t;
        if (ahead >= 2)      asm volatile("s_waitcnt vmcnt(8)" ::: "memory");
        else if (ahead == 1) asm volatile("s_waitcnt vmcnt(4)" ::: "memory");
        else                 asm volatile("s_waitcnt vmcnt(0)" ::: "memory");
        __builtin_amdgcn_s_barrier();
        __builtin_amdgcn_sched_barrier(0);

        if (t + 3 < nt) stage((t + 3) & 3, t + 3);

        const char* lb = (const char*)&lds[cur][0];
        int kq = (lane >> 4) << 4;
        bf16x8 af[2][2], bfr[2][2];
        #pragma unroll
        for (int m = 0; m < 2; ++m) {
            int row = wr * 32 + m * 16 + (lane & 15);
            #pragma unroll
            for (int kk = 0; kk < 2; ++kk) {
                int addr = row * 128 + ((kq + kk * 64) ^ ((row & 7) << 4));
                af[m][kk] = *(const bf16x8*)(lb + addr);
            }
        }
        #pragma unroll
        for (int n = 0; n < 2; ++n) {
            int row = 64 + wc * 32 + n * 16 + (lane & 15);
            #pragma unroll
            for (int kk = 0; kk < 2; ++kk) {
                int addr = row * 128 + ((kq + kk * 64) ^ ((row & 7) << 4));
                bfr[n][kk] = *(const bf16x8*)(lb + addr);
            }
        }
        __builtin_amdgcn_s_setprio(1);
        #pragma unroll
        for (int m = 0; m < 2; ++m)
            #pragma unroll
            for (int n = 0; n < 2; ++n)
                #pragma unroll
                for (int kk = 0; kk < 2; ++kk)
                    acc[m][n] = __builtin_amdgcn_mfma_f32_16x16x32_bf16(
                        af[m][kk], bfr[n][kk], acc[m][n], 0, 0, 0);
        __builtin_amdgcn_s_setprio(0);
    }

    #pragma unroll
    for (int m = 0; m < 2; ++m) {
        #pragma unroll
        for (int n = 0; n < 2; ++n) {
            #pragma unroll
            for (int j = 0; j < 4; ++j) {
                int row = rowBase + wr * 32 + m * 16 + (lane >> 4) * 4 + j;
                int col = colBase + wc * 32 + n * 16 + (lane & 15);
                if (col < N && row < M) {
                    float v = acc[m][n][j] + bias[col];
                    if (RELU) v = fmaxf(v, 0.f);
                    if (WRITE_BF16)
                        ((ushort*)Cout)[(size_t)row * N + col] = f2bf(v);
                    else
                        ((float*)Cout)[(size_t)row * N + col] = v;
                }
            }
        }
    }
}

// ---------------------------------------------------------------------------
extern "C" void kernel_launch(void* const* d_in, const int* in_sizes, int n_in,
                              void* d_out, int out_size, void* d_ws, size_t ws_size,
                              hipStream_t stream) {
    const float* emb        = (const float*)d_in[0];
    const float* W1         = (const float*)d_in[1];  // [2304,1536]
    const float* b1         = (const float*)d_in[2];
    const float* W2         = (const float*)d_in[3];  // [1536,768]
    const float* b2         = (const float*)d_in[4];
    const float* W3         = (const float*)d_in[5];  // [768,121]
    const float* b3         = (const float*)d_in[6];
    const int* span_masks   = (const int*)d_in[7];
    const int* batch_idx    = (const int*)d_in[8];
    const int* aspect_idx   = (const int*)d_in[9];
    const int* opinion_idx  = (const int*)d_in[10];
    float* out = (float*)d_out;                       // [1024,121]

    // workspace (ushort units); H2 aliases Xb (Xb dead after GEMM1)
    ushort* Xb  = (ushort*)d_ws;                        // 2,359,296
    ushort* H2  = Xb;
    ushort* W1t = Xb  + (size_t)1024 * 2304;            // 3,538,944
    ushort* W2t = W1t + (size_t)1536 * 2304;            // 1,179,648
    ushort* W3t = W2t + (size_t)768 * 1536;             // 98,304
    ushort* H1  = W3t + (size_t)128 * 768;              // 1,572,864

    // one prep launch: pb units + W1 transpose (624 blocks, single sched round)
    fused_prep_kernel<<<PB_UNITS + T1_UNITS, 256, 0, stream>>>(
        emb, span_masks, batch_idx, aspect_idx, opinion_idx, Xb, W1, W1t);

    // GEMM1 + W2/W3 transposes hidden in its idle CUs
    gemm1_plus_t23<<<G1_TILES + T2_UNITS + T3_UNITS, 256, 0, stream>>>(
        Xb, W1t, b1, H1, W2, W2t, W3, W3t);

    gemm_mfma<1,1><<<dim3( 768/64, 1024/64), 256, 0, stream>>>(H1, W2t, b2, H2, 1024, 768, 1536);
    gemm_mfma<0,0><<<dim3( 128/64, 1024/64), 256, 0, stream>>>(H2, W3t, b3, out, 1024, 121, 768);
}

// Round 20
// 52.461 us; speedup vs baseline: 1.0312x; 1.0312x over previous
//
#include <hip/hip_runtime.h>
#include <hip/hip_bf16.h>
#include <math.h>

#define S_LEN 128
#define D_DIM 768
#define P_PAIRS 1024
#define B_BATCH 16

typedef __attribute__((ext_vector_type(8))) short bf16x8;
typedef __attribute__((ext_vector_type(4))) float f32x4;

#define PB_UNITS (B_BATCH * (D_DIM / 64))           // 192
#define T1_UNITS ((2304 / 64) * (1536 / 64))        // 36*24 = 864
#define T2_UNITS ((1536 / 64) * (768 / 64))         // 24*12 = 288
#define T3_UNITS ((768 / 64) * (128 / 64))          // 12*2  = 24
#define G1_TILES (24 * 16)                          // 384 GEMM1 tiles

union SmemU {
    struct {
        ushort semb[128][64];    // emb chunk, bf16-rounded
        ushort spref[128][64];   // prefix max (bf16)
        ushort ssuf[128][64];    // suffix max (bf16)
        ushort smean[64];
        float  lred[3][4][64];
        int    li;
    } pb;                        // ~52.4 KB -> 3 blocks/CU
    float t64[64][65];           // transpose tile (16.6 KB)
};

union GSmem {
    ushort lds[4][128 * 64];     // GEMM 4-buffer (64 KB)
    float  t64[64][65];          // transpose tile
};

__device__ __forceinline__ ushort f2bf(float f) {
    __hip_bfloat16 h = __float2bfloat16(f);
    return *(ushort*)&h;
}

__device__ __forceinline__ float bf2f(ushort u) {
    unsigned int x = ((unsigned int)u) << 16;
    float f;
    __builtin_memcpy(&f, &x, 4);
    return f;
}

__device__ __forceinline__ void gload16(const void* g, void* l) {
    __builtin_amdgcn_global_load_lds(
        (const __attribute__((address_space(1))) void*)g,
        (__attribute__((address_space(3))) void*)l, 16, 0, 0);
}

// ---------------------------------------------------------------------------
// 64x64 transpose unit body: in[K,N] f32 -> out[Npad,K] bf16 (zero-pad n>=N)
// ---------------------------------------------------------------------------
__device__ __forceinline__ void transpose_unit(
    float (*t64)[65], const float* __restrict__ in, ushort* __restrict__ out,
    int K, int N, int Npad, int bx, int by, int tid)
{
    int k0 = bx * 64, n0 = by * 64;

    int kr = tid >> 2;
    int nq = (tid & 3) * 16;
    if (n0 + 64 <= N) {
        #pragma unroll
        for (int j = 0; j < 4; ++j) {
            float4 vv = *(const float4*)&in[(size_t)(k0 + kr) * N + n0 + nq + j * 4];
            *(float4*)&t64[kr][nq + j * 4] = vv;
        }
    } else {
        #pragma unroll
        for (int j = 0; j < 16; ++j) {
            int n = n0 + nq + j;
            t64[kr][nq + j] = (n < N) ? in[(size_t)(k0 + kr) * N + n] : 0.f;
        }
    }
    __syncthreads();

    int nr = tid >> 2;
    int kq = (tid & 3) * 16;
    if (n0 + nr < Npad) {
        ushort tmp[16];
        #pragma unroll
        for (int j = 0; j < 16; ++j) tmp[j] = f2bf(t64[kq + j][nr]);
        ushort* dst = out + (size_t)(n0 + nr) * K + k0 + kq;
        *(bf16x8*)dst       = *(bf16x8*)&tmp[0];
        *(bf16x8*)(dst + 8) = *(bf16x8*)&tmp[8];
    }
}

// ---------------------------------------------------------------------------
// Fused prep kernel (round-14 proven bodies).
//   blocks [0,192):     per-(batch, 64-col-chunk) span scan + X build
//   blocks [192,1056):  W1 transpose (64x64 tiles)
// (T2/T3 transposes moved into GEMM1's launch — they are only needed by
//  GEMM2/3, and GEMM1's 384 blocks leave 64 CUs idle to absorb them.)
// ---------------------------------------------------------------------------
__global__ __launch_bounds__(256) void fused_prep_kernel(
    const float* __restrict__ emb_all,   // [B,S,D]
    const int* __restrict__ span_masks,  // [B,S]
    const int* __restrict__ batch_idx,   // [P]
    const int* __restrict__ aspect_idx,  // [P]
    const int* __restrict__ opinion_idx, // [P]
    ushort* __restrict__ X,              // [P, 3*D] bf16
    const float* __restrict__ W1, ushort* __restrict__ W1t)
{
    __shared__ SmemU sm;
    __shared__ int wsum[4];
    int bid = blockIdx.x;
    int tid = threadIdx.x;

    if (bid < PB_UNITS) {
        // ================= span scan + X build =================
        int b = bid / (D_DIM / 64);
        int chunk = bid % (D_DIM / 64);
        int lane = tid & 63;
        int g = tid >> 6;           // wave/row-group 0..3
        int r0 = g * 32;
        int col = chunk * 64 + lane;

        // parallel li: one mask element per thread, shfl+LDS tree reduce
        {
            int mv = (tid < S_LEN) ? span_masks[b * S_LEN + tid] : 0;
            #pragma unroll
            for (int off = 32; off > 0; off >>= 1)
                mv += __shfl_down(mv, off);
            if (lane == 0) wsum[g] = mv;
            __syncthreads();
            if (tid == 0) sm.pb.li = wsum[0] + wsum[1] + wsum[2] + wsum[3] - 1;
            __syncthreads();
        }
        int li = sm.pb.li;

        const float* embb = emb_all + (size_t)b * S_LEN * D_DIM;

        float v[32];
        #pragma unroll
        for (int r = 0; r < 32; ++r) {
            v[r] = embb[(size_t)(r0 + r) * D_DIM + col];
            sm.pb.semb[r0 + r][lane] = f2bf(v[r]);
        }

        float wmax = -INFINITY, umax = -INFINITY, s = 0.f;
        #pragma unroll
        for (int r = 0; r < 32; ++r) {
            int gr = r0 + r;
            wmax = fmaxf(wmax, (gr == 0) ? -INFINITY : v[r]);
            bool in = (gr >= 1) && (gr < li);
            umax = fmaxf(umax, in ? v[r] : -INFINITY);
            s += in ? v[r] : 0.f;
        }
        sm.pb.lred[0][g][lane] = wmax;
        sm.pb.lred[1][g][lane] = umax;
        sm.pb.lred[2][g][lane] = s;
        __syncthreads();

        float basep = -INFINITY;
        #pragma unroll
        for (int gg = 0; gg < 3; ++gg)
            if (gg < g) basep = fmaxf(basep, sm.pb.lred[0][gg][lane]);
        float bases = -INFINITY;
        #pragma unroll
        for (int gg = 1; gg < 4; ++gg)
            if (gg > g) bases = fmaxf(bases, sm.pb.lred[1][gg][lane]);

        if (g == 0) {
            float tot = sm.pb.lred[2][0][lane] + sm.pb.lred[2][1][lane]
                      + sm.pb.lred[2][2][lane] + sm.pb.lred[2][3][lane];
            int cnt = (li - 1) > 0 ? (li - 1) : 1;
            sm.pb.smean[lane] = f2bf(tot / (float)cnt);
        }

        float m = basep;
        #pragma unroll
        for (int r = 0; r < 32; ++r) {
            int gr = r0 + r;
            m = fmaxf(m, (gr == 0) ? -INFINITY : v[r]);
            sm.pb.spref[gr][lane] = f2bf(m);
        }
        float m2 = bases;
        #pragma unroll
        for (int r = 31; r >= 0; --r) {
            int gr = r0 + r;
            bool in = (gr >= 1) && (gr < li);
            m2 = fmaxf(m2, in ? v[r] : -INFINITY);
            if (gr >= 1) sm.pb.ssuf[gr][lane] = f2bf(m2);
        }
        __syncthreads();

        // pair loop: wave g scans pairs [g*256, (g+1)*256), ballot over batch
        int pbase = g * 256;
        for (int c = 0; c < 256; c += 64) {
            int p = pbase + c + lane;
            int vb = batch_idx[p];
            int va = aspect_idx[p];
            int vo = opinion_idx[p];
            unsigned long long mask = __ballot(vb == b);
            while (mask) {
                int i = __ffsll((long long)mask) - 1;
                mask &= mask - 1;
                int pp = pbase + c + i;
                int a = __shfl(va, i);
                int o = __shfl(vo, i);
                bool both0 = (a == 0) && (o == 0);
                int bnd = (a != 0) ? a : o;
                int oe = (o == 0) ? li : o;
                float ar  = bf2f(sm.pb.semb[a][lane]);
                float orp = bf2f(sm.pb.semb[oe][lane]);
                ushort left, right;
                if (both0) {
                    left  = sm.pb.smean[lane];
                    right = sm.pb.spref[li - 1][lane];
                } else {
                    left  = (bnd == 1)  ? sm.pb.semb[0][lane]
                                        : sm.pb.spref[bnd - 1][lane];
                    right = (bnd == li) ? sm.pb.semb[li][lane]
                                        : sm.pb.ssuf[bnd][lane];
                }
                size_t base = (size_t)pp * (3 * D_DIM) + col;
                X[base]             = f2bf(ar + orp);
                X[base + D_DIM]     = left;
                X[base + 2 * D_DIM] = right;
            }
        }
    } else {
        // ================= W1 transpose (64x64 tiles) =================
        int tb = bid - PB_UNITS;
        transpose_unit(sm.t64, W1, W1t, 2304, 1536, 1536, tb % 36, tb / 36, tid);
    }
}

// ---------------------------------------------------------------------------
// GEMM1 launch: blocks [0,384) = MFMA 64x64 tiles (round-14 proven body);
// blocks [384,696) = W2/W3 transposes (outputs needed only by GEMM2/3 —
// stream order guarantees completion before they launch).
// ---------------------------------------------------------------------------
__global__ __launch_bounds__(256, 2) void gemm1_plus_t23(
    const ushort* __restrict__ A,    // X [1024,2304] bf16
    const ushort* __restrict__ Bt,   // W1t [1536,2304] bf16
    const float* __restrict__ bias,  // b1 [1536]
    ushort* __restrict__ Cout,       // H1 [1024,1536] bf16
    const float* __restrict__ W2, ushort* __restrict__ W2t,
    const float* __restrict__ W3, ushort* __restrict__ W3t)
{
    constexpr int M = 1024, N = 1536, K = 2304;
    __shared__ GSmem gs;
    int bid = blockIdx.x;
    int tid = threadIdx.x;

    if (bid >= G1_TILES) {
        int tb = bid - G1_TILES;
        if (tb < T2_UNITS)
            transpose_unit(gs.t64, W2, W2t, 1536, 768, 768, tb % 24, tb / 24, tid);
        else {
            tb -= T2_UNITS;
            transpose_unit(gs.t64, W3, W3t, 768, 121, 128, tb % 12, tb / 12, tid);
        }
        return;
    }

    int lane = tid & 63;
    int w = tid >> 6;
    int wr = w >> 1, wc = w & 1;
    int bx = bid % 24, by = bid / 24;
    int rowBase = by * 64;
    int colBase = bx * 64;

    int srow  = lane >> 3;
    int scolb = (((lane & 7) ^ srow) << 4);
    const char* Abase = (const char*)(A  + (size_t)rowBase * K);
    const char* Bbase = (const char*)(Bt + (size_t)colBase * K);
    size_t rstride = (size_t)K * 2;

    f32x4 acc[2][2] = {};
    int nt = K >> 6;

    auto stage = [&](int buf, int t) {
        size_t kb0 = (size_t)t << 7;
        #pragma unroll
        for (int i = 0; i < 2; ++i) {
            int r = w * 16 + i * 8 + srow;
            gload16(Abase + (size_t)r * rstride + kb0 + scolb,
                    &gs.lds[buf][(w * 16 + i * 8) * 64]);
        }
        #pragma unroll
        for (int i = 0; i < 2; ++i) {
            int r = w * 16 + i * 8 + srow;
            gload16(Bbase + (size_t)r * rstride + kb0 + scolb,
                    &gs.lds[buf][(64 + w * 16 + i * 8) * 64]);
        }
    };

    stage(0, 0);
    stage(1, 1);
    stage(2, 2);

    for (int t = 0; t < nt; ++t) {
        int cur = t & 3;
        int ahead = nt - 1 - t;
        if (ahead >= 2)      asm volatile("s_waitcnt vmcnt(8)" ::: "memory");
        else if (ahead == 1) asm volatile("s_waitcnt vmcnt(4)" ::: "memory");
        else                 asm volatile("s_waitcnt vmcnt(0)" ::: "memory");
        __builtin_amdgcn_s_barrier();
        __builtin_amdgcn_sched_barrier(0);

        if (t + 3 < nt) stage((t + 3) & 3, t + 3);

        const char* lb = (const char*)&gs.lds[cur][0];
        int kq = (lane >> 4) << 4;
        bf16x8 af[2][2], bfr[2][2];
        #pragma unroll
        for (int m = 0; m < 2; ++m) {
            int row = wr * 32 + m * 16 + (lane & 15);
            #pragma unroll
            for (int kk = 0; kk < 2; ++kk) {
                int addr = row * 128 + ((kq + kk * 64) ^ ((row & 7) << 4));
                af[m][kk] = *(const bf16x8*)(lb + addr);
            }
        }
        #pragma unroll
        for (int n = 0; n < 2; ++n) {
            int row = 64 + wc * 32 + n * 16 + (lane & 15);
            #pragma unroll
            for (int kk = 0; kk < 2; ++kk) {
                int addr = row * 128 + ((kq + kk * 64) ^ ((row & 7) << 4));
                bfr[n][kk] = *(const bf16x8*)(lb + addr);
            }
        }
        __builtin_amdgcn_s_setprio(1);
        #pragma unroll
        for (int m = 0; m < 2; ++m)
            #pragma unroll
            for (int n = 0; n < 2; ++n)
                #pragma unroll
                for (int kk = 0; kk < 2; ++kk)
                    acc[m][n] = __builtin_amdgcn_mfma_f32_16x16x32_bf16(
                        af[m][kk], bfr[n][kk], acc[m][n], 0, 0, 0);
        __builtin_amdgcn_s_setprio(0);
    }

    #pragma unroll
    for (int m = 0; m < 2; ++m) {
        #pragma unroll
        for (int n = 0; n < 2; ++n) {
            #pragma unroll
            for (int j = 0; j < 4; ++j) {
                int row = rowBase + wr * 32 + m * 16 + (lane >> 4) * 4 + j;
                int col = colBase + wc * 32 + n * 16 + (lane & 15);
                float v = fmaxf(acc[m][n][j] + bias[col], 0.f);
                Cout[(size_t)row * N + col] = f2bf(v);
            }
        }
    }
}

// ---------------------------------------------------------------------------
// GEMM2/3 (round-14 proven body): 64x64 tile, 4 waves, depth-3 pipeline.
// ---------------------------------------------------------------------------
template<int WRITE_BF16, int RELU>
__global__ __launch_bounds__(256, 2) void gemm_mfma(
    const ushort* __restrict__ A,    // [M,K] bf16
    const ushort* __restrict__ Bt,   // [Npad,K] bf16
    const float* __restrict__ bias,  // [N]
    void* __restrict__ Cout,         // [M,N]
    int M, int N, int K)
{
    __shared__ ushort lds[4][128 * 64];
    int tid = threadIdx.x;
    int lane = tid & 63;
    int w = tid >> 6;
    int wr = w >> 1, wc = w & 1;
    int rowBase = blockIdx.y * 64;
    int colBase = blockIdx.x * 64;

    int srow  = lane >> 3;
    int scolb = (((lane & 7) ^ srow) << 4);
    const char* Abase = (const char*)(A  + (size_t)rowBase * K);
    const char* Bbase = (const char*)(Bt + (size_t)colBase * K);
    size_t rstride = (size_t)K * 2;

    f32x4 acc[2][2] = {};
    int nt = K >> 6;

    auto stage = [&](int buf, int t) {
        size_t kb0 = (size_t)t << 7;
        #pragma unroll
        for (int i = 0; i < 2; ++i) {
            int r = w * 16 + i * 8 + srow;
            gload16(Abase + (size_t)r * rstride + kb0 + scolb,
                    &lds[buf][(w * 16 + i * 8) * 64]);
        }
        #pragma unroll
        for (int i = 0; i < 2; ++i) {
            int r = w * 16 + i * 8 + srow;
            gload16(Bbase + (size_t)r * rstride + kb0 + scolb,
                    &lds[buf][(64 + w * 16 + i * 8) * 64]);
        }
    };

    stage(0, 0);
    stage(1, 1);
    stage(2, 2);

    for (int t = 0; t < nt; ++t) {
        int cur = t & 3;
        int ahead = nt - 1 - t;
        if (ahead >= 2)      asm volatile("s_waitcnt vmcnt(8)" ::: "memory");
        else if (ahead == 1) asm volatile("s_waitcnt vmcnt(4)" ::: "memory");
        else                 asm volatile("s_waitcnt vmcnt(0)" ::: "memory");
        __builtin_amdgcn_s_barrier();
        __builtin_amdgcn_sched_barrier(0);

        if (t + 3 < nt) stage((t + 3) & 3, t + 3);

        const char* lb = (const char*)&lds[cur][0];
        int kq = (lane >> 4) << 4;
        bf16x8 af[2][2], bfr[2][2];
        #pragma unroll
        for (int m = 0; m < 2; ++m) {
            int row = wr * 32 + m * 16 + (lane & 15);
            #pragma unroll
            for (int kk = 0; kk < 2; ++kk) {
                int addr = row * 128 + ((kq + kk * 64) ^ ((row & 7) << 4));
                af[m][kk] = *(const bf16x8*)(lb + addr);
            }
        }
        #pragma unroll
        for (int n = 0; n < 2; ++n) {
            int row = 64 + wc * 32 + n * 16 + (lane & 15);
            #pragma unroll
            for (int kk = 0; kk < 2; ++kk) {
                int addr = row * 128 + ((kq + kk * 64) ^ ((row & 7) << 4));
                bfr[n][kk] = *(const bf16x8*)(lb + addr);
            }
        }
        __builtin_amdgcn_s_setprio(1);
        #pragma unroll
        for (int m = 0; m < 2; ++m)
            #pragma unroll
            for (int n = 0; n < 2; ++n)
                #pragma unroll
                for (int kk = 0; kk < 2; ++kk)
                    acc[m][n] = __builtin_amdgcn_mfma_f32_16x16x32_bf16(
                        af[m][kk], bfr[n][kk], acc[m][n], 0, 0, 0);
        __builtin_amdgcn_s_setprio(0);
    }

    #pragma unroll
    for (int m = 0; m < 2; ++m) {
        #pragma unroll
        for (int n = 0; n < 2; ++n) {
            #pragma unroll
            for (int j = 0; j < 4; ++j) {
                int row = rowBase + wr * 32 + m * 16 + (lane >> 4) * 4 + j;
                int col = colBase + wc * 32 + n * 16 + (lane & 15);
                if (col < N && row < M) {
                    float v = acc[m][n][j] + bias[col];
                    if (RELU) v = fmaxf(v, 0.f);
                    if (WRITE_BF16)
                        ((ushort*)Cout)[(size_t)row * N + col] = f2bf(v);
                    else
                        ((float*)Cout)[(size_t)row * N + col] = v;
                }
            }
        }
    }
}

// ---------------------------------------------------------------------------
extern "C" void kernel_launch(void* const* d_in, const int* in_sizes, int n_in,
                              void* d_out, int out_size, void* d_ws, size_t ws_size,
                              hipStream_t stream) {
    const float* emb        = (const float*)d_in[0];
    const float* W1         = (const float*)d_in[1];  // [2304,1536]
    const float* b1         = (const float*)d_in[2];
    const float* W2         = (const float*)d_in[3];  // [1536,768]
    const float* b2         = (const float*)d_in[4];
    const float* W3         = (const float*)d_in[5];  // [768,121]
    const float* b3         = (const float*)d_in[6];
    const int* span_masks   = (const int*)d_in[7];
    const int* batch_idx    = (const int*)d_in[8];
    const int* aspect_idx   = (const int*)d_in[9];
    const int* opinion_idx  = (const int*)d_in[10];
    float* out = (float*)d_out;                       // [1024,121]

    // workspace (ushort units); H2 aliases Xb (Xb dead after GEMM1)
    ushort* Xb  = (ushort*)d_ws;                        // 2,359,296
    ushort* H2  = Xb;
    ushort* W1t = Xb  + (size_t)1024 * 2304;            // 3,538,944
    ushort* W2t = W1t + (size_t)1536 * 2304;            // 1,179,648
    ushort* W3t = W2t + (size_t)768 * 1536;             // 98,304
    ushort* H1  = W3t + (size_t)128 * 768;              // 1,572,864

    // one prep launch: pb units + W1 transpose (1056 blocks)
    fused_prep_kernel<<<PB_UNITS + T1_UNITS, 256, 0, stream>>>(
        emb, span_masks, batch_idx, aspect_idx, opinion_idx, Xb, W1, W1t);

    // GEMM1 + W2/W3 transposes hidden in its idle CUs
    gemm1_plus_t23<<<G1_TILES + T2_UNITS + T3_UNITS, 256, 0, stream>>>(
        Xb, W1t, b1, H1, W2, W2t, W3, W3t);

    gemm_mfma<1,1><<<dim3( 768/64, 1024/64), 256, 0, stream>>>(H1, W2t, b2, H2, 1024, 768, 1536);
    gemm_mfma<0,0><<<dim3( 128/64, 1024/64), 256, 0, stream>>>(H2, W3t, b3, out, 1024, 121, 768);
}